// Round 21
// baseline (170.829 us; speedup 1.0000x reference)
//
#include <hip/hip_runtime.h>
#include <hip/hip_bf16.h>
#include <stdint.h>

#define BATCH 8192
#define PEP 15
#define INC 512
#define OUTC 512
#define XROW (PEP*INC)          // 7680 floats per batch row
#define WT_P_ELEMS (INC*OUTC)   // 262144 bf16 per p
#define NSTEPS 8                // K = 512 = 8 x 64

typedef float f32x4 __attribute__((ext_vector_type(4)));
typedef short s16x8 __attribute__((ext_vector_type(8)));
typedef unsigned int u32x4 __attribute__((ext_vector_type(4)));

__device__ __forceinline__ ushort f2b(float v) {
  uint u = __float_as_uint(v);
  u += 0x7fffu + ((u >> 16) & 1u);
  return (ushort)(u >> 16);
}

__device__ __forceinline__ uint cvtpk(float a, float b) {
  // D[15:0]=bf16(a), D[31:16]=bf16(b); RNE. No builtin on gfx950 (T12 recipe).
  uint r;
  asm("v_cvt_pk_bf16_f32 %0, %1, %2" : "=v"(r) : "v"(a), "v"(b));
  return r;
}

// ---------------- kernel 1: coalesced W -> fragment-linear bf16 (verified R19) --------
// wt[(((p*16+ks32)*32+n16)*64+l)*8+e] = bf16(W[p][ks32*32+(l>>4)*8+e][n16*16+(l&15)])
__global__ __launch_bounds__(256) void wt_kernel(const float* __restrict__ w,
                                                 ushort* __restrict__ wt) {
  __shared__ float tile[32 * 133];
  const int t = threadIdx.x;
  const int bid = blockIdx.x;        // 960 = 15p x 16ks x 4nchunk
  const int nchunk = bid & 3;
  const int ks     = (bid >> 2) & 15;
  const int p      = bid >> 6;

  const float* src = w + (size_t)p * WT_P_ELEMS + (size_t)(ks * 32) * OUTC + nchunk * 128;
  const int rk = t >> 5;
  const int rc = (t & 31) * 4;
#pragma unroll
  for (int i = 0; i < 4; ++i) {
    const int k = rk + i * 8;
    f32x4 v = *(const f32x4*)(src + (size_t)k * OUTC + rc);
    *(f32x4*)&tile[k * 133 + rc] = v;
  }
  __syncthreads();

  ushort* dst = wt + ((size_t)(p * 16 + ks) * 32 + nchunk * 8) * 512;
#pragma unroll
  for (int h = 0; h < 2; ++h) {
    const int f   = t + h * 256;
    const int n16 = f >> 6;
    const int l   = f & 63;
    const int fr  = l & 15;
    const int g   = l >> 4;
    s16x8 hv;
#pragma unroll
    for (int e = 0; e < 8; ++e)
      hv[e] = (short)f2b(tile[(g * 8 + e) * 133 + n16 * 16 + fr]);
    *(s16x8*)(dst + (size_t)n16 * 512 + l * 8) = hv;
  }
}

// ---------------- kernel 2: counted-vmcnt GEMM, BK=64, deep flight, NO vmcnt(0) -------
// BM=128 x BN=256 x BK=64, 512 thr (8 waves; wave (wm,wn) owns 64m x 64n).
// B: global_load_lds, TRIPLE-buffered, issued 2 iters ahead (~2-iter flight);
//    drained by counted vmcnt(8) at iter end — loads survive barriers.
// A: global->reg ring depth-2 (2-iter flight, compiler-counted waits) -> cvt_pk ->
//    double-buffered LDS one iter ahead. One raw s_barrier + lgkmcnt(0) per iter.
__global__ __launch_bounds__(512, 2) void gemm_kernel(const float* __restrict__ x,
                                                      const ushort* __restrict__ wt,
                                                      const float* __restrict__ bias,
                                                      float* __restrict__ out) {
  extern __shared__ __align__(16) char lds_raw[];              // 128 KB dynamic
  auto Ash = (ushort (*)[8][2][64][8])lds_raw;                 // [Abuf][m16][ksub][lane][e] 2x16KB
  auto Bsh = (ushort (*)[2][16][64][8])(lds_raw + 32768);      // [Bbuf][ksub][n16][lane][e] 3x32KB

  const int t    = threadIdx.x;
  const int lane = t & 63;
  const int wid  = t >> 6;        // 0..7
  const int wm   = wid >> 2;      // 0..1 : m-half
  const int wn   = wid & 3;       // 0..3 : n-quarter
  const int fr   = lane & 15;
  const int g    = lane >> 4;

  // grid: 1920 = 8 xcd * 240; j&1 = n-half (adjacent -> x L2-share), mb-major, p slow.
  const int bid  = blockIdx.x;
  const int xcd  = bid & 7;
  const int j    = bid >> 3;               // 0..239
  const int n2   = j & 1;
  const int pair = xcd * 120 + (j >> 1);   // 0..959 = 64 mb x 15 p
  const int mb   = pair & 63;
  const int p    = pair >> 6;
  const int m0   = mb * 128;

  // A: wave wid stages m16-block wid; lane (fr,g): row m0+wid*16+fr, col base g*8.
  const float* asrc = x + (size_t)(m0 + wid * 16 + fr) * XROW + p * INC + g * 8;
  // B: wave wid stages chunks c = wid*4+q (32 chunks = 2 ksub x 16 n16).
  const ushort* wt_p = wt + (size_t)p * WT_P_ELEMS + (size_t)lane * 8;

  f32x4 acc[4][4] = {};             // [m16][nf]: 64 regs
  f32x4 pa[2][2][2];                // [ring][ksub][half]: 32 regs

  auto load_pa = [&](int ks, int ring) {
#pragma unroll
    for (int ksub = 0; ksub < 2; ++ksub) {
      pa[ring][ksub][0] = *(const f32x4*)(asrc + ks * 64 + ksub * 32);
      pa[ring][ksub][1] = *(const f32x4*)(asrc + ks * 64 + ksub * 32 + 4);
    }
  };
  auto cvt_store = [&](int ring, int buf) {
#pragma unroll
    for (int ksub = 0; ksub < 2; ++ksub) {
      u32x4 aw;
      aw[0] = cvtpk(pa[ring][ksub][0][0], pa[ring][ksub][0][1]);
      aw[1] = cvtpk(pa[ring][ksub][0][2], pa[ring][ksub][0][3]);
      aw[2] = cvtpk(pa[ring][ksub][1][0], pa[ring][ksub][1][1]);
      aw[3] = cvtpk(pa[ring][ksub][1][2], pa[ring][ksub][1][3]);
      *(u32x4*)&Ash[buf][wid][ksub][lane][0] = aw;
    }
  };
  auto stageB = [&](int ks, int buf) {
#pragma unroll
    for (int q = 0; q < 4; ++q) {
      const int c    = wid * 4 + q;       // 0..31
      const int ksb  = c >> 4;
      const int n16l = c & 15;
      __builtin_amdgcn_global_load_lds(
          (const __attribute__((address_space(1))) void*)
            (wt_p + ((size_t)(ks * 2 + ksb) * 32 + n2 * 16 + n16l) * 512),
          (__attribute__((address_space(3))) void*)(&Bsh[buf][ksb][n16l][lane][0]),
          16, 0, 0);
    }
  };

  // ---- prologue: order pinned A(0) | B(0) | B(1) | A(1); cvt A(0); vmcnt(8) barrier
  load_pa(0, 0);
  __builtin_amdgcn_sched_barrier(0);
  stageB(0, 0);
  __builtin_amdgcn_sched_barrier(0);
  stageB(1, 1);
  __builtin_amdgcn_sched_barrier(0);
  load_pa(1, 1);
  __builtin_amdgcn_sched_barrier(0);
  cvt_store(0, 0);                       // compiler-counted wait on A(0) only
  __builtin_amdgcn_sched_barrier(0);
  asm volatile("s_waitcnt vmcnt(8)" ::: "memory");   // drain B(0); keep B(1)+A(1)
  asm volatile("s_waitcnt lgkmcnt(0)" ::: "memory");
  __builtin_amdgcn_s_barrier();
  __builtin_amdgcn_sched_barrier(0);

#pragma unroll
  for (int ks = 0; ks < NSTEPS; ++ks) {
    // (a,b) issue A(ks+2) and B(ks+2): full-iteration+ flight before their drains
    if (ks + 2 < NSTEPS) {
      load_pa(ks + 2, ks & 1);
      stageB(ks + 2, (ks + 2) % 3);
    }
    __builtin_amdgcn_sched_barrier(0);

    // (d) cvt A(ks+1) -> Ash[(ks+1)&1] (ring slot (ks+1)&1; compiler-counted vmcnt)
    if (ks + 1 < NSTEPS) cvt_store((ks + 1) & 1, (ks + 1) & 1);
    __builtin_amdgcn_sched_barrier(0);

    // (e,g) fragments + MFMA per ksub (all LDS reads lane-contiguous, conflict-free)
    __builtin_amdgcn_s_setprio(1);
#pragma unroll
    for (int ksub = 0; ksub < 2; ++ksub) {
      s16x8 af[4], bf[4];
#pragma unroll
      for (int i = 0; i < 4; ++i)
        af[i] = *(const s16x8*)&Ash[ks & 1][wm * 4 + i][ksub][lane][0];
#pragma unroll
      for (int nf = 0; nf < 4; ++nf)
        bf[nf] = *(const s16x8*)&Bsh[ks % 3][ksub][wn * 4 + nf][lane][0];
#pragma unroll
      for (int i = 0; i < 4; ++i)
#pragma unroll
        for (int nf = 0; nf < 4; ++nf)
          acc[i][nf] = __builtin_amdgcn_mfma_f32_16x16x32_bf16(af[i], bf[nf], acc[i][nf], 0, 0, 0);
    }
    __builtin_amdgcn_s_setprio(0);
    __builtin_amdgcn_sched_barrier(0);

    // (h) counted drain: B(ks+1) must be landed before next iter's ds_read.
    // outstanding: B(ks+1)[4 oldest], A(ks+2)[4], B(ks+2)[4] -> vmcnt(8), never 0
    // except the tail (ks==6: only B(7) outstanding).
    if (ks < 6)       asm volatile("s_waitcnt vmcnt(8)" ::: "memory");
    else if (ks == 6) asm volatile("s_waitcnt vmcnt(0)" ::: "memory");
    asm volatile("s_waitcnt lgkmcnt(0)" ::: "memory");
    __builtin_amdgcn_s_barrier();
    __builtin_amdgcn_sched_barrier(0);
  }

  // ---- epilogue: block-cooperative row assembly -> 1KB-contiguous NT bursts ----
  // C/D layout col=lane&15, row=(lane>>4)*4+r (m89-verified). R17-verified epilogue.
  const int n0q = wn * 64;
  float bv[4];
#pragma unroll
  for (int nf = 0; nf < 4; ++nf) bv[nf] = bias[p * OUTC + n2 * 256 + n0q + nf * 16 + fr];

  float* reg0 = (float*)lds_raw;                 // region[0]: 16 x 260 f32
  float* reg1 = (float*)lds_raw + 16 * 260;      // region[1]
  float* myreg = wm ? reg1 : reg0;
  const float* obase = out + p * INC + n2 * 256 + lane * 4;

#pragma unroll
  for (int s = 0; s < 4; ++s) {
    __builtin_amdgcn_sched_barrier(0);
#pragma unroll
    for (int nf = 0; nf < 4; ++nf)
#pragma unroll
      for (int r = 0; r < 4; ++r)
        myreg[(g * 4 + r) * 260 + n0q + nf * 16 + fr] = acc[s][nf][r] + bv[nf];
    __builtin_amdgcn_sched_barrier(0);
    asm volatile("s_waitcnt lgkmcnt(0)" ::: "memory");
    __builtin_amdgcn_s_barrier();
    __builtin_amdgcn_sched_barrier(0);

#pragma unroll
    for (int pass = 0; pass < 4; ++pass) {
      const int row_id = pass * 8 + wid;        // 0..31
      const int rgn = row_id >> 4;
      const int rw  = row_id & 15;
      f32x4 v = *(const f32x4*)((rgn ? reg1 : reg0) + rw * 260 + lane * 4);
      __builtin_nontemporal_store(v,
          (f32x4*)((float*)obase + (size_t)(m0 + rgn * 64 + s * 16 + rw) * XROW));
    }
    __builtin_amdgcn_sched_barrier(0);
    asm volatile("s_waitcnt lgkmcnt(0)" ::: "memory");
    __builtin_amdgcn_s_barrier();
    __builtin_amdgcn_sched_barrier(0);
  }
}

// ---------------- fallback (only if ws/LDS unavailable): naive fp32 ----------------
__global__ void naive_kernel(const float* __restrict__ x, const float* __restrict__ w,
                             const float* __restrict__ bias, float* __restrict__ out) {
  size_t i = (size_t)blockIdx.x * 256 + threadIdx.x;
  if (i >= (size_t)BATCH * PEP * OUTC) return;
  int o  = (int)(i & (OUTC - 1));
  int pp = (int)((i >> 9) % PEP);
  size_t b = i / ((size_t)PEP * OUTC);
  const float* xr = x + b * XROW + pp * INC;
  const float* wc = w + (size_t)pp * INC * OUTC + o;
  float s = bias[pp * OUTC + o];
  for (int k = 0; k < INC; ++k) s += xr[k] * wc[(size_t)k * OUTC];
  out[i] = s;
}

extern "C" void kernel_launch(void* const* d_in, const int* in_sizes, int n_in,
                              void* d_out, int out_size, void* d_ws, size_t ws_size,
                              hipStream_t stream) {
  const float* x    = (const float*)d_in[0];
  const float* w    = (const float*)d_in[1];
  const float* bias = (const float*)d_in[2];
  float* out = (float*)d_out;

  const size_t wt_bytes = (size_t)PEP * INC * OUTC * sizeof(ushort);  // 7.9 MB
  static int lds_ok = -1;
  if (lds_ok < 0) {
    hipError_t e = hipFuncSetAttribute(reinterpret_cast<const void*>(gemm_kernel),
                                       hipFuncAttributeMaxDynamicSharedMemorySize, 131072);
    lds_ok = (e == hipSuccess) ? 1 : 0;
  }
  if (ws_size >= wt_bytes && lds_ok == 1) {
    wt_kernel<<<960, 256, 0, stream>>>(w, (ushort*)d_ws);
    gemm_kernel<<<1920, 512, 131072, stream>>>(x, (const ushort*)d_ws, bias, out);
  } else {
    size_t total = (size_t)BATCH * PEP * OUTC;
    naive_kernel<<<(int)((total + 255) / 256), 256, 0, stream>>>(x, w, bias, out);
  }
}

// Round 22
// 144.736 us; speedup vs baseline: 1.1803x; 1.1803x over previous
//
#include <hip/hip_runtime.h>
#include <hip/hip_bf16.h>
#include <stdint.h>

#define BATCH 8192
#define PEP 15
#define INC 512
#define OUTC 512
#define XROW (PEP*INC)          // 7680 floats per batch row
#define WT_P_ELEMS (INC*OUTC)   // 262144 bf16 per p
#define NSTEPS 16               // K = 512 = 16 x 32

typedef float f32x4 __attribute__((ext_vector_type(4)));
typedef short s16x8 __attribute__((ext_vector_type(8)));
typedef unsigned int u32x4 __attribute__((ext_vector_type(4)));

__device__ __forceinline__ ushort f2b(float v) {
  uint u = __float_as_uint(v);
  u += 0x7fffu + ((u >> 16) & 1u);
  return (ushort)(u >> 16);
}

__device__ __forceinline__ uint cvtpk(float a, float b) {
  // D[15:0]=bf16(a), D[31:16]=bf16(b); RNE. No builtin on gfx950 (T12 recipe).
  uint r;
  asm("v_cvt_pk_bf16_f32 %0, %1, %2" : "=v"(r) : "v"(a), "v"(b));
  return r;
}

// ---------------- kernel 1: coalesced W -> fragment-linear bf16 (verified R19) --------
// wt[(((p*16+ks)*32+n16)*64+l)*8+e] = bf16(W[p][ks*32+(l>>4)*8+e][n16*16+(l&15)])
__global__ __launch_bounds__(256) void wt_kernel(const float* __restrict__ w,
                                                 ushort* __restrict__ wt) {
  __shared__ float tile[32 * 133];
  const int t = threadIdx.x;
  const int bid = blockIdx.x;        // 960 = 15p x 16ks x 4nchunk
  const int nchunk = bid & 3;
  const int ks     = (bid >> 2) & 15;
  const int p      = bid >> 6;

  const float* src = w + (size_t)p * WT_P_ELEMS + (size_t)(ks * 32) * OUTC + nchunk * 128;
  const int rk = t >> 5;
  const int rc = (t & 31) * 4;
#pragma unroll
  for (int i = 0; i < 4; ++i) {
    const int k = rk + i * 8;
    f32x4 v = *(const f32x4*)(src + (size_t)k * OUTC + rc);
    *(f32x4*)&tile[k * 133 + rc] = v;
  }
  __syncthreads();

  ushort* dst = wt + ((size_t)(p * 16 + ks) * 32 + nchunk * 8) * 512;
#pragma unroll
  for (int h = 0; h < 2; ++h) {
    const int f   = t + h * 256;
    const int n16 = f >> 6;
    const int l   = f & 63;
    const int fr  = l & 15;
    const int g   = l >> 4;
    s16x8 hv;
#pragma unroll
    for (int e = 0; e < 8; ++e)
      hv[e] = (short)f2b(tile[(g * 8 + e) * 133 + n16 * 16 + fr]);
    *(s16x8*)(dst + (size_t)n16 * 512 + l * 8) = hv;
  }
}

// ---------------- kernel 2: R17 geometry + counted-vmcnt flight (B triple-buffered) ---
// BM=128 x BN=256 x BK=32, 512 thr (8 waves; wave (wm,wn) owns 64m x 64n).
// B: global_load_lds, TRIPLE-buffered, staged 2 iters ahead; drained by vmcnt(4)
//    (never 0 until tail) -> ~2-iteration flight ACROSS raw s_barriers.
// A: pa regs (1-iter flight, compiler-counted wait at cvt) -> cvt_pk -> linear ds_write.
// LDS 64KB static (A 2x8K | B 3x16K) -> 2 blocks/CU; VGPR plan identical to R17 (64).
__global__ __launch_bounds__(512, 4) void gemm_kernel(const float* __restrict__ x,
                                                      const ushort* __restrict__ wt,
                                                      const float* __restrict__ bias,
                                                      float* __restrict__ out) {
  __shared__ __align__(16) char lds_raw[65536];
  auto Ash = (ushort (*)[8][64][8])lds_raw;              // [2][m16][lane][e]  16 KB
  auto Bsh = (ushort (*)[16][64][8])(lds_raw + 16384);   // [3][n16][lane][e]  48 KB

  const int t    = threadIdx.x;
  const int lane = t & 63;
  const int wid  = t >> 6;        // 0..7
  const int wm   = wid >> 2;      // 0..1 : m-half
  const int wn   = wid & 3;       // 0..3 : n-quarter
  const int fr   = lane & 15;
  const int g    = lane >> 4;

  // grid: 1920 = 8 xcd * 240; j&1 = n-half (adjacent -> x L2-share), mb-major, p slow.
  const int bid  = blockIdx.x;
  const int xcd  = bid & 7;
  const int j    = bid >> 3;               // 0..239
  const int n2   = j & 1;
  const int pair = xcd * 120 + (j >> 1);   // 0..959 = 64 mb x 15 p
  const int mb   = pair & 63;
  const int p    = pair >> 6;
  const int m0   = mb * 128;

  const float* asrc = x + (size_t)(m0 + wid * 16 + fr) * XROW + p * INC + g * 8;
  const ushort* bsrc = wt + (size_t)p * WT_P_ELEMS
                     + (size_t)(n2 * 16 + wid * 2) * 512 + (size_t)lane * 8;

  f32x4 acc[4][4] = {};             // [m16][nf] (AGPR side)
  f32x4 pa0, pa1;                   // A staging regs

  auto cvt_store = [&](int buf) {
    u32x4 aw;
    aw[0] = cvtpk(pa0[0], pa0[1]); aw[1] = cvtpk(pa0[2], pa0[3]);
    aw[2] = cvtpk(pa1[0], pa1[1]); aw[3] = cvtpk(pa1[2], pa1[3]);
    *(u32x4*)&Ash[buf][wid][lane][0] = aw;
  };
  auto stageB = [&](int ks, int buf) {
#pragma unroll
    for (int q = 0; q < 2; ++q) {
      __builtin_amdgcn_global_load_lds(
          (const __attribute__((address_space(1))) void*)(bsrc + (size_t)ks * 16384 + q * 512),
          (__attribute__((address_space(3))) void*)(&Bsh[buf][wid * 2 + q][lane][0]),
          16, 0, 0);
    }
  };

  // ---- prologue: A(0)->pa->Ash[0]; A(1)->pa; B(0),B(1) staged; drain B(0) only
  pa0 = *(const f32x4*)(asrc);
  pa1 = *(const f32x4*)(asrc + 4);
  cvt_store(0);                                  // compiler waits A(0) only
  __builtin_amdgcn_sched_barrier(0);
  pa0 = *(const f32x4*)(asrc + 32);
  pa1 = *(const f32x4*)(asrc + 36);
  __builtin_amdgcn_sched_barrier(0);
  stageB(0, 0);
  stageB(1, 1);
  __builtin_amdgcn_sched_barrier(0);
  asm volatile("s_waitcnt vmcnt(2)" ::: "memory");   // drain B(0); keep A(1)+... B(1) in flight
  asm volatile("s_waitcnt lgkmcnt(0)" ::: "memory");
  __builtin_amdgcn_s_barrier();
  __builtin_amdgcn_sched_barrier(0);

#pragma unroll
  for (int ks = 0; ks < NSTEPS; ++ks) {
    const int cur  = ks & 1;
    const int curB = ks % 3;

    // (1) cvt A(ks+1) -> Ash[(ks+1)&1]  (reads pa from prev iter; compiler-counted)
    if (ks + 1 < NSTEPS) cvt_store((ks + 1) & 1);
    __builtin_amdgcn_sched_barrier(0);

    // (2) refill pa with A(ks+2)  (AFTER cvt so the cvt's wait excludes it)
    if (ks + 2 < NSTEPS) {
      pa0 = *(const f32x4*)(asrc + (ks + 2) * 32);
      pa1 = *(const f32x4*)(asrc + (ks + 2) * 32 + 4);
    }
    __builtin_amdgcn_sched_barrier(0);

    // (3) stage B(ks+2) -> Bsh[(ks+2)%3]  (2-iteration flight; slot safe: its old
    //     content B(ks-1) was fully read before the iter-(ks-1) barrier)
    if (ks + 2 < NSTEPS) stageB(ks + 2, (ks + 2) % 3);
    __builtin_amdgcn_sched_barrier(0);

    // (4) fragments (lane-contiguous, conflict-free) + MFMA
    s16x8 af[4], bf[4];
#pragma unroll
    for (int i = 0; i < 4; ++i)
      af[i] = *(const s16x8*)&Ash[cur][wm * 4 + i][lane][0];
#pragma unroll
    for (int nf = 0; nf < 4; ++nf)
      bf[nf] = *(const s16x8*)&Bsh[curB][wn * 4 + nf][lane][0];

    __builtin_amdgcn_s_setprio(1);
#pragma unroll
    for (int i = 0; i < 4; ++i)
#pragma unroll
      for (int nf = 0; nf < 4; ++nf)
        acc[i][nf] = __builtin_amdgcn_mfma_f32_16x16x32_bf16(af[i], bf[nf], acc[i][nf], 0, 0, 0);
    __builtin_amdgcn_s_setprio(0);
    __builtin_amdgcn_sched_barrier(0);

    // (5) counted drain: complete B(ks+1) (issued iter ks-1); keep A(ks+2)+B(ks+2)
    if (ks <= 13)      asm volatile("s_waitcnt vmcnt(4)" ::: "memory");
    else if (ks == 14) asm volatile("s_waitcnt vmcnt(0)" ::: "memory");
    asm volatile("s_waitcnt lgkmcnt(0)" ::: "memory");
    __builtin_amdgcn_s_barrier();
    __builtin_amdgcn_sched_barrier(0);
  }

  // ---- epilogue: block-cooperative row assembly -> 1KB-contiguous NT bursts ----
  // C/D layout col=lane&15, row=(lane>>4)*4+r (m89-verified). R17-verified epilogue.
  const int n0q = wn * 64;
  float bv[4];
#pragma unroll
  for (int nf = 0; nf < 4; ++nf) bv[nf] = bias[p * OUTC + n2 * 256 + n0q + nf * 16 + fr];

  float* reg0 = (float*)lds_raw;                 // region[0]: 16 x 260 f32
  float* reg1 = (float*)lds_raw + 16 * 260;      // region[1]
  float* myreg = wm ? reg1 : reg0;
  const float* obase = out + p * INC + n2 * 256 + lane * 4;

#pragma unroll
  for (int s = 0; s < 4; ++s) {
    __builtin_amdgcn_sched_barrier(0);
#pragma unroll
    for (int nf = 0; nf < 4; ++nf)
#pragma unroll
      for (int r = 0; r < 4; ++r)
        myreg[(g * 4 + r) * 260 + n0q + nf * 16 + fr] = acc[s][nf][r] + bv[nf];
    __builtin_amdgcn_sched_barrier(0);
    asm volatile("s_waitcnt lgkmcnt(0)" ::: "memory");
    __builtin_amdgcn_s_barrier();
    __builtin_amdgcn_sched_barrier(0);

#pragma unroll
    for (int pass = 0; pass < 4; ++pass) {
      const int row_id = pass * 8 + wid;        // 0..31
      const int rgn = row_id >> 4;
      const int rw  = row_id & 15;
      f32x4 v = *(const f32x4*)((rgn ? reg1 : reg0) + rw * 260 + lane * 4);
      __builtin_nontemporal_store(v,
          (f32x4*)((float*)obase + (size_t)(m0 + rgn * 64 + s * 16 + rw) * XROW));
    }
    __builtin_amdgcn_sched_barrier(0);
    asm volatile("s_waitcnt lgkmcnt(0)" ::: "memory");
    __builtin_amdgcn_s_barrier();
    __builtin_amdgcn_sched_barrier(0);
  }
}

// ---------------- fallback (only if ws too small): naive fp32 ----------------
__global__ void naive_kernel(const float* __restrict__ x, const float* __restrict__ w,
                             const float* __restrict__ bias, float* __restrict__ out) {
  size_t i = (size_t)blockIdx.x * 256 + threadIdx.x;
  if (i >= (size_t)BATCH * PEP * OUTC) return;
  int o  = (int)(i & (OUTC - 1));
  int pp = (int)((i >> 9) % PEP);
  size_t b = i / ((size_t)PEP * OUTC);
  const float* xr = x + b * XROW + pp * INC;
  const float* wc = w + (size_t)pp * INC * OUTC + o;
  float s = bias[pp * OUTC + o];
  for (int k = 0; k < INC; ++k) s += xr[k] * wc[(size_t)k * OUTC];
  out[i] = s;
}

extern "C" void kernel_launch(void* const* d_in, const int* in_sizes, int n_in,
                              void* d_out, int out_size, void* d_ws, size_t ws_size,
                              hipStream_t stream) {
  const float* x    = (const float*)d_in[0];
  const float* w    = (const float*)d_in[1];
  const float* bias = (const float*)d_in[2];
  float* out = (float*)d_out;

  const size_t wt_bytes = (size_t)PEP * INC * OUTC * sizeof(ushort);  // 7.9 MB
  if (ws_size >= wt_bytes) {
    wt_kernel<<<960, 256, 0, stream>>>(w, (ushort*)d_ws);
    gemm_kernel<<<1920, 512, 0, stream>>>(x, (const ushort*)d_ws, bias, out);
  } else {
    size_t total = (size_t)BATCH * PEP * OUTC;
    naive_kernel<<<(int)((total + 255) / 256), 256, 0, stream>>>(x, w, bias, out);
  }
}

// Round 23
// 141.014 us; speedup vs baseline: 1.2114x; 1.0264x over previous
//
#include <hip/hip_runtime.h>
#include <hip/hip_bf16.h>
#include <stdint.h>

#define BATCH 8192
#define PEP 15
#define INC 512
#define OUTC 512
#define XROW (PEP*INC)          // 7680 floats per batch row
#define WT_P_ELEMS (INC*OUTC)   // 262144 bf16 per p
#define NSTEPS 16               // K = 512 = 16 x 32

typedef float f32x4 __attribute__((ext_vector_type(4)));
typedef short s16x8 __attribute__((ext_vector_type(8)));
typedef unsigned int u32x2 __attribute__((ext_vector_type(2)));

__device__ __forceinline__ ushort f2b(float v) {
  uint u = __float_as_uint(v);
  u += 0x7fffu + ((u >> 16) & 1u);
  return (ushort)(u >> 16);
}

__device__ __forceinline__ uint cvtpk(float a, float b) {
  // D[15:0]=bf16(a), D[31:16]=bf16(b); RNE. No builtin on gfx950 (T12 recipe).
  uint r;
  asm("v_cvt_pk_bf16_f32 %0, %1, %2" : "=v"(r) : "v"(a), "v"(b));
  return r;
}

// ---------------- kernel 1: coalesced W -> fragment-linear bf16 (verified R19) --------
// wt[(((p*16+ks)*32+n16)*64+l)*8+e] = bf16(W[p][ks*32+(l>>4)*8+e][n16*16+(l&15)])
__global__ __launch_bounds__(256) void wt_kernel(const float* __restrict__ w,
                                                 ushort* __restrict__ wt) {
  __shared__ float tile[32 * 133];
  const int t = threadIdx.x;
  const int bid = blockIdx.x;        // 960 = 15p x 16ks x 4nchunk
  const int nchunk = bid & 3;
  const int ks     = (bid >> 2) & 15;
  const int p      = bid >> 6;

  const float* src = w + (size_t)p * WT_P_ELEMS + (size_t)(ks * 32) * OUTC + nchunk * 128;
  const int rk = t >> 5;
  const int rc = (t & 31) * 4;
#pragma unroll
  for (int i = 0; i < 4; ++i) {
    const int k = rk + i * 8;
    f32x4 v = *(const f32x4*)(src + (size_t)k * OUTC + rc);
    *(f32x4*)&tile[k * 133 + rc] = v;
  }
  __syncthreads();

  ushort* dst = wt + ((size_t)(p * 16 + ks) * 32 + nchunk * 8) * 512;
#pragma unroll
  for (int h = 0; h < 2; ++h) {
    const int f   = t + h * 256;
    const int n16 = f >> 6;
    const int l   = f & 63;
    const int fr  = l & 15;
    const int g   = l >> 4;
    s16x8 hv;
#pragma unroll
    for (int e = 0; e < 8; ++e)
      hv[e] = (short)f2b(tile[(g * 8 + e) * 133 + n16 * 16 + fr]);
    *(s16x8*)(dst + (size_t)n16 * 512 + l * 8) = hv;
  }
}

// ---------------- kernel 2: BM=128 x BN=512, 16-wave block, max occupancy -------------
// 960 blocks x 1024 thr; 2 blocks/CU = 32 waves/CU (8/SIMD, max TLP).
// Wave (wm,wn) owns 64m x 64n. BN=512: each 2KB out row written ONCE by one wave;
// x read once globally. A: f32x4/thread -> cvt_pk -> ds_write_b64 fragment-linear.
// B: global_load_lds double-buffer; counted vmcnt(1) drains; raw barrier + lgkm only.
__global__ __launch_bounds__(1024, 2) void gemm_kernel(const float* __restrict__ x,
                                                       const ushort* __restrict__ wt,
                                                       const float* __restrict__ bias,
                                                       float* __restrict__ out) {
  __shared__ __align__(16) char lds_raw[81920];          // A 2x8KB | B 2x32KB
  auto Ash = (ushort (*)[8][64][8])lds_raw;              // [buf][m16][slot][e]
  auto Bsh = (ushort (*)[32][64][8])(lds_raw + 16384);   // [buf][n16][lane][e]

  const int t    = threadIdx.x;
  const int lane = t & 63;
  const int wid  = t >> 6;        // 0..15
  const int wm   = wid >> 3;      // 0..1 : m-half
  const int wn   = wid & 7;       // 0..7 : n-eighth
  const int fr   = lane & 15;
  const int g    = lane >> 4;

  // grid: 960 = 8 xcd * 120; mb-major within XCD (wt slice L2-resident), p slow.
  const int bid  = blockIdx.x;
  const int xcd  = bid & 7;
  const int j    = bid >> 3;             // 0..119
  const int pair = xcd * 120 + j;        // 0..959 = 64 mb x 15 p
  const int mb   = pair & 63;
  const int p    = pair >> 6;
  const int m0   = mb * 128;

  // ---- A staging: thread -> one f32x4. row = t>>3 (0..127), kq = t&7 (col kq*4).
  const int arow  = t >> 3;
  const int kq    = t & 7;
  const float* asrc = x + (size_t)(m0 + arow) * XROW + p * INC + kq * 4;
  const int am16  = arow >> 4;
  const int aslot = (arow & 15) + 16 * (kq >> 1);
  const int aeoff = (kq & 1) * 4;        // elem offset (x2B = byte 0 or 8)

  // ---- B DMA: wave wid stages n16 = wid*2 + q (32 chunks of 1KB per K-step)
  const ushort* bsrc = wt + (size_t)p * WT_P_ELEMS + (size_t)(wid * 2) * 512 + (size_t)lane * 8;

  f32x4 acc[4][4] = {};             // [m16][nf] for this wave's 64x64 tile
  f32x4 pa;                          // A staging reg (4 floats)

  auto cvt_store = [&](int buf) {
    u32x2 aw;
    aw[0] = cvtpk(pa[0], pa[1]);
    aw[1] = cvtpk(pa[2], pa[3]);
    *(u32x2*)&Ash[buf][am16][aslot][aeoff] = aw;
  };
  auto stageB = [&](int ks, int buf) {
#pragma unroll
    for (int q = 0; q < 2; ++q) {
      __builtin_amdgcn_global_load_lds(
          (const __attribute__((address_space(1))) void*)(bsrc + (size_t)ks * 16384 + q * 512),
          (__attribute__((address_space(3))) void*)(&Bsh[buf][wid * 2 + q][lane][0]),
          16, 0, 0);
    }
  };

  // ---- prologue: A(0)->Ash[0]; B(0) staged; A(1)->pa; drain B(0), keep pa
  pa = *(const f32x4*)(asrc);
  cvt_store(0);
  __builtin_amdgcn_sched_barrier(0);
  stageB(0, 0);
  __builtin_amdgcn_sched_barrier(0);
  pa = *(const f32x4*)(asrc + 32);
  __builtin_amdgcn_sched_barrier(0);
  asm volatile("s_waitcnt vmcnt(1)" ::: "memory");   // B(0) landed; A(1) in flight
  asm volatile("s_waitcnt lgkmcnt(0)" ::: "memory");
  __builtin_amdgcn_s_barrier();
  __builtin_amdgcn_sched_barrier(0);

#pragma unroll
  for (int ks = 0; ks < NSTEPS; ++ks) {
    const int cur = ks & 1;
    const int nxt = cur ^ 1;

    // (1) cvt A(ks+1) -> Ash[nxt]  (pa loaded last iter; compiler-counted wait)
    if (ks + 1 < NSTEPS) cvt_store(nxt);
    __builtin_amdgcn_sched_barrier(0);

    // (2) stage B(ks+1) -> Bsh[nxt]
    if (ks + 1 < NSTEPS) stageB(ks + 1, nxt);
    __builtin_amdgcn_sched_barrier(0);

    // (3) refill pa with A(ks+2)
    if (ks + 2 < NSTEPS) pa = *(const f32x4*)(asrc + (ks + 2) * 32);
    __builtin_amdgcn_sched_barrier(0);

    // (4) fragments (lane-contiguous, conflict-free) + MFMA
    s16x8 af[4], bf[4];
#pragma unroll
    for (int i = 0; i < 4; ++i)
      af[i] = *(const s16x8*)&Ash[cur][wm * 4 + i][lane][0];
#pragma unroll
    for (int nf = 0; nf < 4; ++nf)
      bf[nf] = *(const s16x8*)&Bsh[cur][wn * 4 + nf][lane][0];

    __builtin_amdgcn_s_setprio(1);
#pragma unroll
    for (int i = 0; i < 4; ++i)
#pragma unroll
      for (int nf = 0; nf < 4; ++nf)
        acc[i][nf] = __builtin_amdgcn_mfma_f32_16x16x32_bf16(af[i], bf[nf], acc[i][nf], 0, 0, 0);
    __builtin_amdgcn_s_setprio(0);
    __builtin_amdgcn_sched_barrier(0);

    // (5) counted drain: B(ks+1) complete; keep pa A(ks+2) in flight. Never vmcnt(0)
    //     except tail (ks=14: only B(15) outstanding).
    if (ks <= 13)      asm volatile("s_waitcnt vmcnt(1)" ::: "memory");
    else if (ks == 14) asm volatile("s_waitcnt vmcnt(0)" ::: "memory");
    asm volatile("s_waitcnt lgkmcnt(0)" ::: "memory");
    __builtin_amdgcn_s_barrier();
    __builtin_amdgcn_sched_barrier(0);
  }

  // ---- epilogue: block-cooperative full-row assembly -> 2KB-contiguous NT writes ----
  // C/D layout col=lane&15, row=(lane>>4)*4+r (m89-verified).
  // Step s: waves deposit acc[s] (m16=wm*4+s) into region[wm] (16 x pitch-520 f32);
  // then wave w writes rows w*2, w*2+1 — each 2KB contiguous (two adjacent 1KB NT).
  float bv[4];
#pragma unroll
  for (int nf = 0; nf < 4; ++nf) bv[nf] = bias[p * OUTC + wn * 64 + nf * 16 + fr];

  float* region0 = (float*)lds_raw;              // 16 x 520 f32 (33.3 KB)
  float* region1 = region0 + 16 * 520;           // second region
  float* myreg = wm ? region1 : region0;

#pragma unroll
  for (int s = 0; s < 4; ++s) {
    __builtin_amdgcn_sched_barrier(0);
#pragma unroll
    for (int nf = 0; nf < 4; ++nf)
#pragma unroll
      for (int r = 0; r < 4; ++r)
        myreg[(g * 4 + r) * 520 + wn * 64 + nf * 16 + fr] = acc[s][nf][r] + bv[nf];
    __builtin_amdgcn_sched_barrier(0);
    asm volatile("s_waitcnt lgkmcnt(0)" ::: "memory");
    __builtin_amdgcn_s_barrier();
    __builtin_amdgcn_sched_barrier(0);

#pragma unroll
    for (int rr = 0; rr < 2; ++rr) {
      const int row_id = wid * 2 + rr;          // 0..31
      const int rgn = row_id >> 4;              // m-half
      const int rw  = row_id & 15;
      const float* srcrow = (rgn ? region1 : region0) + rw * 520;
      float* dst = out + (size_t)(m0 + rgn * 64 + s * 16 + rw) * XROW + p * INC;
      f32x4 v0 = *(const f32x4*)(srcrow + lane * 4);
      f32x4 v1 = *(const f32x4*)(srcrow + 256 + lane * 4);
      __builtin_nontemporal_store(v0, (f32x4*)(dst + lane * 4));
      __builtin_nontemporal_store(v1, (f32x4*)(dst + 256 + lane * 4));
    }
    __builtin_amdgcn_sched_barrier(0);
    asm volatile("s_waitcnt lgkmcnt(0)" ::: "memory");   // reads landed before next deposit
    __builtin_amdgcn_s_barrier();
    __builtin_amdgcn_sched_barrier(0);
  }
}

// ---------------- fallback (only if ws too small): naive fp32 ----------------
__global__ void naive_kernel(const float* __restrict__ x, const float* __restrict__ w,
                             const float* __restrict__ bias, float* __restrict__ out) {
  size_t i = (size_t)blockIdx.x * 256 + threadIdx.x;
  if (i >= (size_t)BATCH * PEP * OUTC) return;
  int o  = (int)(i & (OUTC - 1));
  int pp = (int)((i >> 9) % PEP);
  size_t b = i / ((size_t)PEP * OUTC);
  const float* xr = x + b * XROW + pp * INC;
  const float* wc = w + (size_t)pp * INC * OUTC + o;
  float s = bias[pp * OUTC + o];
  for (int k = 0; k < INC; ++k) s += xr[k] * wc[(size_t)k * OUTC];
  out[i] = s;
}

extern "C" void kernel_launch(void* const* d_in, const int* in_sizes, int n_in,
                              void* d_out, int out_size, void* d_ws, size_t ws_size,
                              hipStream_t stream) {
  const float* x    = (const float*)d_in[0];
  const float* w    = (const float*)d_in[1];
  const float* bias = (const float*)d_in[2];
  float* out = (float*)d_out;

  const size_t wt_bytes = (size_t)PEP * INC * OUTC * sizeof(ushort);  // 7.9 MB
  if (ws_size >= wt_bytes) {
    wt_kernel<<<960, 256, 0, stream>>>(w, (ushort*)d_ws);
    gemm_kernel<<<960, 1024, 0, stream>>>(x, (const ushort*)d_ws, bias, out);
  } else {
    size_t total = (size_t)BATCH * PEP * OUTC;
    naive_kernel<<<(int)((total + 255) / 256), 256, 0, stream>>>(x, w, bias, out);
  }
}